// Round 5
// baseline (224.163 us; speedup 1.0000x reference)
//
#include <hip/hip_runtime.h>
#include <hip/hip_bf16.h>

// ---------------------------------------------------------------------------
// TwoSimplicialAttention  (B=2, T=192, C=512, H=8, D=64)
// R5: attn: logit MFMA operand-flipped (A=K1, B=Q*k2) so P lands in registers
//     as P[i=c][j=jt*16+q*4+r]; with a chosen V1 column permutation the PV
//     A-frags are packed ENTIRELY IN-LANE (no P LDS round-trip at all).
//     K1 in LDS [192][68], V1 in LDS [64][196] (both bank-balanced), k2/v2
//     from global. LDS 51.2KB -> 3 blocks/CU co-resident (launch_bounds 256,3).
//     proj/outp: 4-wave blocks, intra-block K-split (wave K=128), LDS combine.
// ---------------------------------------------------------------------------

typedef float  v4f __attribute__((ext_vector_type(4)));
typedef short  v8s __attribute__((ext_vector_type(8)));

__device__ __forceinline__ unsigned short f2bf(float f) {
  unsigned u = __float_as_uint(f);
  u += 0x7fffu + ((u >> 16) & 1u);       // RNE
  return (unsigned short)(u >> 16);
}
__device__ __forceinline__ float bf2f(unsigned short b) {
  return __uint_as_float(((unsigned)b) << 16);
}
__device__ __forceinline__ unsigned pack_bf16(float lo, float hi) {
  __hip_bfloat162 t = __float22bfloat162_rn(float2{lo, hi});
  union { __hip_bfloat162 b; unsigned u; } cv;
  cv.b = t;
  return cv.u;
}

#if __has_builtin(__builtin_amdgcn_exp2f)
#define EXP2F(x) __builtin_amdgcn_exp2f(x)
#else
#define EXP2F(x) exp2f(x)
#endif

#define MFMA32(a, b, c) __builtin_amdgcn_mfma_f32_16x16x32_bf16((a), (b), (c), 0, 0, 0)

// q scale = D^-0.5 * log2(e)
#define QSCALE 0.18033688011112042f

// ws layout, floats (wsf):
//   qs   [16][192][64]        @ 0        (q * 0.125*log2e, fp32)
//   v2p  [16][192][16][4]     @ 196608   ([.][k][c][r] = v2[d=c+16r], fp32)
//   accp [16][12][4][16][64]  @ 393216
//   Sp   [16][12][4][16]      @ 1179648  (total fp32: 1191936)
// ws layout, ushort (wsh = wsf + 1191936):
//   k1b  [16][192][64]  @ 0
//   k2b  [16][192][64]  @ 196608
//   v1t  [16][64][192]  @ 393216   (columns in sigma-order, see v1perm)
//   xh   [384][512]     @ 589824      xl @ 786432
//   Wth  [2560][512]    @ 983040      Wtl @ 2293760   (W_in^T, k-major)
//   Woth [512][512]     @ 3604480     Wotl @ 3866624  (W_out^T, k-major)
//   oh   [384][512]     @ 4128768     ol  @ 4325376   (normalized out)

#define XH_OFF   589824
#define XL_OFF   786432
#define WTH_OFF  983040
#define WTL_OFF  2293760
#define WOTH_OFF 3604480
#define WOTL_OFF 3866624
#define OH_OFF   4128768
#define OL_OFF   4325376

// sigma: V1 column position p for actual j index t (0..191).
// Derived so that PV A-frag dword w of m-group m = pack(C[2m+(w>>1)][(w&1)*2 +{0,1}])
// is built in-lane from the flipped-logit MFMA output registers.
__device__ __forceinline__ int v1perm(int t) {
  const int h = (t >= 96) ? 1 : 0;
  const int jh = t - 96 * h;
  const int jtl = jh >> 4, rem = jh & 15;
  const int m = jtl >> 1;
  const int w = ((jtl & 1) << 1) | ((rem >> 1) & 1);
  const int k = ((rem >> 2) << 3) | (w << 1) | (rem & 1);
  return h * 96 + m * 32 + k;
}

// ------------------------------ Phase 0: prep ------------------------------
__global__ __launch_bounds__(256) void prep_kernel(
    const float* __restrict__ x, const float* __restrict__ Win,
    const float* __restrict__ Wout, unsigned short* __restrict__ wsh) {
  __shared__ float tile[32 * 65];
  const int bi = blockIdx.x, t = threadIdx.x;
  if (bi < 768) {
    const float* W; unsigned short *Th, *Tl; int R, n0, k0;
    if (bi < 640) {
      W = Win; Th = wsh + WTH_OFF; Tl = wsh + WTL_OFF; R = 2560;
      n0 = (bi % 40) << 6; k0 = (bi / 40) << 5;
    } else {
      const int idx = bi - 640;
      W = Wout; Th = wsh + WOTH_OFF; Tl = wsh + WOTL_OFF; R = 512;
      n0 = (idx & 7) << 6; k0 = (idx >> 3) << 5;
    }
    const int n = t & 63, kq = (t >> 6) * 8;
#pragma unroll
    for (int j = 0; j < 8; ++j)
      tile[(kq + j) * 65 + n] = W[(k0 + kq + j) * R + n0 + n];
    __syncthreads();
    const int n2 = t >> 2, ks = (t & 3) * 8;
    union { uint4 u; unsigned short us[8]; } ph, pl;
#pragma unroll
    for (int j = 0; j < 8; ++j) {
      const float v = tile[(ks + j) * 65 + n2];
      const unsigned short h = f2bf(v);
      ph.us[j] = h;
      pl.us[j] = f2bf(v - bf2f(h));
    }
    *(uint4*)(Th + (n0 + n2) * 512 + k0 + ks) = ph.u;
    *(uint4*)(Tl + (n0 + n2) * 512 + k0 + ks) = pl.u;
  } else {
    const int flat = ((bi - 768) * 256 + t) * 8;
    const v4f v0 = *(const v4f*)(x + flat);
    const v4f v1 = *(const v4f*)(x + flat + 4);
    union { uint4 u; unsigned short us[8]; } ph, pl;
#pragma unroll
    for (int j = 0; j < 4; ++j) {
      unsigned short h = f2bf(v0[j]);
      ph.us[j] = h; pl.us[j] = f2bf(v0[j] - bf2f(h));
      h = f2bf(v1[j]);
      ph.us[4 + j] = h; pl.us[4 + j] = f2bf(v1[j] - bf2f(h));
    }
    *(uint4*)(wsh + XH_OFF + flat) = ph.u;
    *(uint4*)(wsh + XL_OFF + flat) = pl.u;
  }
}

// ------------------------------ Phase 1: proj (bf16x3 MFMA) ----------------
// grid (12, 80) x 256 thr: 4 waves split K=512 (128 each), 32x32 C-tile,
// fp32 combine through LDS.
__global__ __launch_bounds__(256) void proj_kernel(
    const unsigned short* __restrict__ wsh, const float* __restrict__ bin,
    float* __restrict__ wsf, unsigned short* __restrict__ wshd) {
  __shared__ float red[4][32][33];
  const int tid = threadIdx.x;
  const int wv = tid >> 6, lane = tid & 63;
  const int c = lane & 15, q = lane >> 4;
  const int bm = blockIdx.x, bn = blockIdx.y;
  const int k0 = wv * 128;

  const unsigned short* base[8];
  base[0] = wsh + XH_OFF + (bm * 32 + c) * 512 + (q << 3) + k0;
  base[1] = base[0] + 16 * 512;
  base[2] = wsh + XL_OFF + (bm * 32 + c) * 512 + (q << 3) + k0;
  base[3] = base[2] + 16 * 512;
  base[4] = wsh + WTH_OFF + (bn * 32 + c) * 512 + (q << 3) + k0;
  base[5] = base[4] + 16 * 512;
  base[6] = wsh + WTL_OFF + (bn * 32 + c) * 512 + (q << 3) + k0;
  base[7] = base[6] + 16 * 512;

  const v4f z = {0.f, 0.f, 0.f, 0.f};
  v4f a00 = z, a01 = z, a10 = z, a11 = z;

  v8s cur[8], nxt[8];
#pragma unroll
  for (int i = 0; i < 8; ++i) cur[i] = *(const v8s*)(base[i]);
#pragma unroll 1
  for (int ks = 0; ks < 4; ++ks) {
    if (ks < 3) {
      const int o = (ks + 1) * 32;
#pragma unroll
      for (int i = 0; i < 8; ++i) nxt[i] = *(const v8s*)(base[i] + o);
    }
    a00 = MFMA32(cur[2], cur[4], a00); a00 = MFMA32(cur[0], cur[6], a00); a00 = MFMA32(cur[0], cur[4], a00);
    a01 = MFMA32(cur[2], cur[5], a01); a01 = MFMA32(cur[0], cur[7], a01); a01 = MFMA32(cur[0], cur[5], a01);
    a10 = MFMA32(cur[3], cur[4], a10); a10 = MFMA32(cur[1], cur[6], a10); a10 = MFMA32(cur[1], cur[4], a10);
    a11 = MFMA32(cur[3], cur[5], a11); a11 = MFMA32(cur[1], cur[7], a11); a11 = MFMA32(cur[1], cur[5], a11);
#pragma unroll
    for (int i = 0; i < 8; ++i) cur[i] = nxt[i];
  }

  v4f accs[2][2] = {{a00, a01}, {a10, a11}};
#pragma unroll
  for (int mt = 0; mt < 2; ++mt)
#pragma unroll
    for (int nt = 0; nt < 2; ++nt)
#pragma unroll
      for (int r = 0; r < 4; ++r)
        red[wv][mt * 16 + (q << 2) + r][nt * 16 + c] = accs[mt][nt][r];
  __syncthreads();

#pragma unroll
  for (int j = 0; j < 4; ++j) {
    const int o = tid + (j << 8);
    const int row = o >> 5, col = o & 31;
    const int n = bn * 32 + col;
    const float val = red[0][row][col] + red[1][row][col] +
                      red[2][row][col] + red[3][row][col] + bin[n];
    const int m = bm * 32 + row;
    const int which = n >> 9, cc = n & 511, hh = cc >> 6, d = cc & 63;
    const int b = (m >= 192) ? 1 : 0;
    const int tt = m - (b ? 192 : 0);
    const int bh = b * 8 + hh;
    const int rm = ((bh * 192 + tt) << 6) + d;
    if (which == 0)      wsf[rm] = val * QSCALE;
    else if (which == 1) wshd[rm] = f2bf(val);
    else if (which == 2) wshd[393216 + ((bh << 6) + d) * 192 + v1perm(tt)] = f2bf(val);
    else if (which == 3) wshd[196608 + rm] = f2bf(val);
    else wsf[196608 + ((bh * 192 + tt) * 16 + (d & 15)) * 4 + (d >> 4)] = val;
  }
}

// ------------------------------ Phase 2: attention -------------------------
// grid = 16(bh)*12(i)*4(ksplit) = 768 blocks, 256 thr (4 waves), 3 blocks/CU.
__global__ __launch_bounds__(256, 3) void attn_kernel(
    const float* __restrict__ wsf, const unsigned short* __restrict__ wsh,
    float* __restrict__ accp, float* __restrict__ Sp) {
  __shared__ unsigned short smem[25600];   // V1s [64][196] + K1s [192][68] = 51200 B
  unsigned short* V1s = smem;
  unsigned short* K1s = smem + 12544;

  const int tid  = threadIdx.x;
  const int wv   = tid >> 6;
  const int lane = tid & 63;
  const int c    = lane & 15;
  const int quad = lane >> 4;

  const int bb = blockIdx.x;
  const int kb = bb & 3;
  const int it = (bb >> 2) % 12;
  const int bh = bb / 48;

  const unsigned short* k1g = wsh + bh * 192 * 64;
  const unsigned short* v1g = wsh + 393216 + bh * 64 * 192;
  const unsigned short* k2g = wsh + 196608 + bh * 192 * 64;
  const float*          v2g = wsf + 196608 + bh * 12288;   // [192][16][4]

  for (int idx = tid; idx < 3072; idx += 256) {
    if (idx < 1536) {
      const int r = idx / 24, c8 = (idx % 24) * 8;
      *(uint4*)(V1s + r * 196 + c8) = *(const uint4*)(v1g + r * 192 + c8);
    } else {
      const int j = idx - 1536;
      const int r = j >> 3, c8 = (j & 7) << 3;
      *(uint4*)(K1s + r * 68 + c8) = *(const uint4*)(k1g + (r << 6) + c8);
    }
  }

  // q rows (fp32, pre-scaled): i = it*16+c, d = quad*8+e (+32)
  const float* qg = wsf + ((bh * 192 + it * 16 + c) << 6) + (quad << 3);
  float q0[8], q1[8];
  {
    v4f qa = *(const v4f*)(qg), qb = *(const v4f*)(qg + 4);
    v4f qc = *(const v4f*)(qg + 32), qd = *(const v4f*)(qg + 36);
#pragma unroll
    for (int e = 0; e < 4; ++e) {
      q0[e] = qa[e]; q0[4 + e] = qb[e];
      q1[e] = qc[e]; q1[4 + e] = qd[e];
    }
  }
  __syncthreads();   // staging done; no barriers until epilogue

  const v4f z = {0.f, 0.f, 0.f, 0.f};
  v4f acc[4] = {z, z, z, z};
  v4f oS = z;
  const short one = (short)0x3F80;
  const v8s ones = {one, one, one, one, one, one, one, one};

  const int kstart = kb * 48 + wv * 12;
  union U4 { uint4 u4; unsigned short us[8]; };
  union AF { v8s v; unsigned u[4]; };

#pragma unroll 1
  for (int p = 0; p < 6; ++p) {
    const int rA = kstart + 2 * p, rB = rA + 1;
    U4 klA, khA, klB, khB;
    klA.u4 = *(const uint4*)(k2g + (rA << 6) + (quad << 3));
    khA.u4 = *(const uint4*)(k2g + (rA << 6) + (quad << 3) + 32);
    klB.u4 = *(const uint4*)(k2g + (rB << 6) + (quad << 3));
    khB.u4 = *(const uint4*)(k2g + (rB << 6) + (quad << 3) + 32);
    const v4f v2A = *(const v4f*)(v2g + (rA << 6) + (c << 2));
    const v4f v2B = *(const v4f*)(v2g + (rB << 6) + (c << 2));

    AF afA0, afA1, afB0, afB1;
#pragma unroll
    for (int e = 0; e < 4; ++e) {
      afA0.u[e] = pack_bf16(q0[2*e] * bf2f(klA.us[2*e]), q0[2*e+1] * bf2f(klA.us[2*e+1]));
      afA1.u[e] = pack_bf16(q1[2*e] * bf2f(khA.us[2*e]), q1[2*e+1] * bf2f(khA.us[2*e+1]));
      afB0.u[e] = pack_bf16(q0[2*e] * bf2f(klB.us[2*e]), q0[2*e+1] * bf2f(klB.us[2*e+1]));
      afB1.u[e] = pack_bf16(q1[2*e] * bf2f(khB.us[2*e]), q1[2*e+1] * bf2f(khB.us[2*e+1]));
    }

#pragma unroll
    for (int h = 0; h < 2; ++h) {
      // logits: A = K1 (m=j), B = Q*k2 (n=i)  ->  lane holds P[i=c][j=jt*16+q*4+r]
      v4f CA[6], CB[6];
#pragma unroll
      for (int j6 = 0; j6 < 6; ++j6) {
        const unsigned short* kp = K1s + ((h * 6 + j6) * 16 + c) * 68 + (quad << 3);
        const v8s k1lo = *(const v8s*)kp;
        const v8s k1hi = *(const v8s*)(kp + 32);
        v4f t0 = MFMA32(k1lo, afA0.v, z);
        CA[j6] = MFMA32(k1hi, afA1.v, t0);
        v4f t1 = MFMA32(k1lo, afB0.v, z);
        CB[j6] = MFMA32(k1hi, afB1.v, t1);
      }
#pragma unroll
      for (int j6 = 0; j6 < 6; ++j6)
#pragma unroll
        for (int r = 0; r < 4; ++r) {
          CA[j6][r] = EXP2F(CA[j6][r]);
          CB[j6][r] = EXP2F(CB[j6][r]);
        }
      // in-lane A-frag construction (sigma-matched to V1 column order)
      AF pA[3], pB[3];
#pragma unroll
      for (int m = 0; m < 3; ++m)
#pragma unroll
        for (int w = 0; w < 4; ++w) {
          const int jt = 2 * m + (w >> 1), r0 = (w & 1) * 2;
          pA[m].u[w] = pack_bf16(CA[jt][r0], CA[jt][r0 + 1]);
          pB[m].u[w] = pack_bf16(CB[jt][r0], CB[jt][r0 + 1]);
        }
      // PV + S; V1 frags shared by ksteps A and B
      v4f oA[4] = {z, z, z, z}, oB[4] = {z, z, z, z};
#pragma unroll
      for (int m = 0; m < 3; ++m) {
        oS = MFMA32(pA[m].v, ones, oS);
        oS = MFMA32(pB[m].v, ones, oS);
        const int vcol = (h * 3 + m) * 32 + (quad << 3);
#pragma unroll
        for (int t = 0; t < 4; ++t) {
          const v8s vf = *(const v8s*)(V1s + (c + 16 * t) * 196 + vcol);
          oA[t] = MFMA32(pA[m].v, vf, oA[t]);
          oB[t] = MFMA32(pB[m].v, vf, oB[t]);
        }
      }
#pragma unroll
      for (int t = 0; t < 4; ++t) acc[t] += oA[t] * v2A[t] + oB[t] * v2B[t];
    }
  }

  __syncthreads();  // reuse smem for cross-wave reduction
  float* redA = (float*)smem;              // [4][16][64]
  float* redS = (float*)smem + 4096;       // [4][16]

  if (c == 0) {
    float* rs = redS + wv * 16 + (quad << 2);
#pragma unroll
    for (int r = 0; r < 4; ++r) rs[r] = oS[r];
  }
#pragma unroll
  for (int r = 0; r < 4; ++r) {
    float* rr = redA + wv * 1024 + (((quad << 2) + r) << 6) + c;
    rr[0] = acc[0][r]; rr[16] = acc[1][r]; rr[32] = acc[2][r]; rr[48] = acc[3][r];
  }
  __syncthreads();

  const int pbase = (bh * 12 + it) * 4 + kb;
  float* ap_out = accp + pbase * 1024;
  for (int idx = tid; idx < 1024; idx += 256)
    ap_out[idx] = redA[idx] + redA[1024 + idx] + redA[2048 + idx] + redA[3072 + idx];
  if (tid < 16)
    Sp[pbase * 16 + tid] = redS[tid] + redS[16 + tid] + redS[32 + tid] + redS[48 + tid];
}

// ------------------------------ Phase 2.5: normalize -----------------------
__global__ __launch_bounds__(256) void norm_kernel(
    const float* __restrict__ accp, const float* __restrict__ Sp,
    unsigned short* __restrict__ wsh) {
  const int flat = blockIdx.x * 2048 + threadIdx.x * 8;
  const int m = flat >> 9, cc = flat & 511;
  const int b = (m >= 192) ? 1 : 0;
  const int tt = m - (b ? 192 : 0);
  const int h = cc >> 6, d0 = cc & 63;
  const int bh = b * 8 + h, it = tt >> 4, i = tt & 15;
  const int pb = (bh * 12 + it) * 4;
  const float* ap = accp + pb * 1024 + (i << 6) + d0;
  v4f a0 = *(const v4f*)(ap), a1 = *(const v4f*)(ap + 4);
  float Sv = Sp[pb * 16 + i];
#pragma unroll
  for (int kb = 1; kb < 4; ++kb) {
    a0 += *(const v4f*)(ap + kb * 1024);
    a1 += *(const v4f*)(ap + kb * 1024 + 4);
    Sv += Sp[(pb + kb) * 16 + i];
  }
  const float inv = 1.0f / Sv;
  union { uint4 u; unsigned short us[8]; } ph, pl;
#pragma unroll
  for (int j = 0; j < 4; ++j) {
    float v = a0[j] * inv;
    unsigned short hh = f2bf(v);
    ph.us[j] = hh; pl.us[j] = f2bf(v - bf2f(hh));
    v = a1[j] * inv;
    hh = f2bf(v);
    ph.us[4 + j] = hh; pl.us[4 + j] = f2bf(v - bf2f(hh));
  }
  *(uint4*)(wsh + OH_OFF + flat) = ph.u;
  *(uint4*)(wsh + OL_OFF + flat) = pl.u;
}

// ------------------------------ Phase 3: out GEMM (bf16x3 MFMA) ------------
// grid (12, 16) x 256 thr: 4 waves split K=512, 32x32 tile, LDS combine.
__global__ __launch_bounds__(256) void outp_kernel(
    const unsigned short* __restrict__ wsh, const float* __restrict__ bout,
    float* __restrict__ y) {
  __shared__ float red[4][32][33];
  const int tid = threadIdx.x;
  const int wv = tid >> 6, lane = tid & 63;
  const int c = lane & 15, q = lane >> 4;
  const int bm = blockIdx.x, bn = blockIdx.y;
  const int k0 = wv * 128;

  const unsigned short* base[8];
  base[0] = wsh + OH_OFF + (bm * 32 + c) * 512 + (q << 3) + k0;
  base[1] = base[0] + 16 * 512;
  base[2] = wsh + OL_OFF + (bm * 32 + c) * 512 + (q << 3) + k0;
  base[3] = base[2] + 16 * 512;
  base[4] = wsh + WOTH_OFF + (bn * 32 + c) * 512 + (q << 3) + k0;
  base[5] = base[4] + 16 * 512;
  base[6] = wsh + WOTL_OFF + (bn * 32 + c) * 512 + (q << 3) + k0;
  base[7] = base[6] + 16 * 512;

  const v4f z = {0.f, 0.f, 0.f, 0.f};
  v4f a00 = z, a01 = z, a10 = z, a11 = z;

  v8s cur[8], nxt[8];
#pragma unroll
  for (int i = 0; i < 8; ++i) cur[i] = *(const v8s*)(base[i]);
#pragma unroll 1
  for (int ks = 0; ks < 4; ++ks) {
    if (ks < 3) {
      const int o = (ks + 1) * 32;
#pragma unroll
      for (int i = 0; i < 8; ++i) nxt[i] = *(const v8s*)(base[i] + o);
    }
    a00 = MFMA32(cur[2], cur[4], a00); a00 = MFMA32(cur[0], cur[6], a00); a00 = MFMA32(cur[0], cur[4], a00);
    a01 = MFMA32(cur[2], cur[5], a01); a01 = MFMA32(cur[0], cur[7], a01); a01 = MFMA32(cur[0], cur[5], a01);
    a10 = MFMA32(cur[3], cur[4], a10); a10 = MFMA32(cur[1], cur[6], a10); a10 = MFMA32(cur[1], cur[4], a10);
    a11 = MFMA32(cur[3], cur[5], a11); a11 = MFMA32(cur[1], cur[7], a11); a11 = MFMA32(cur[1], cur[5], a11);
#pragma unroll
    for (int i = 0; i < 8; ++i) cur[i] = nxt[i];
  }

  v4f accs[2][2] = {{a00, a01}, {a10, a11}};
#pragma unroll
  for (int mt = 0; mt < 2; ++mt)
#pragma unroll
    for (int nt = 0; nt < 2; ++nt)
#pragma unroll
      for (int r = 0; r < 4; ++r)
        red[wv][mt * 16 + (q << 2) + r][nt * 16 + c] = accs[mt][nt][r];
  __syncthreads();

#pragma unroll
  for (int j = 0; j < 4; ++j) {
    const int o = tid + (j << 8);
    const int row = o >> 5, col = o & 31;
    const int n = bn * 32 + col;
    const float val = red[0][row][col] + red[1][row][col] +
                      red[2][row][col] + red[3][row][col] + bout[n];
    y[(bm * 32 + row) * 512 + n] = val;
  }
}

// ------------------------------ launcher -----------------------------------
extern "C" void kernel_launch(void* const* d_in, const int* in_sizes, int n_in,
                              void* d_out, int out_size, void* d_ws, size_t ws_size,
                              hipStream_t stream) {
  const float* x    = (const float*)d_in[0];
  const float* Win  = (const float*)d_in[1];
  const float* bin  = (const float*)d_in[2];
  const float* Wout = (const float*)d_in[3];
  const float* bout = (const float*)d_in[4];

  float* wsf = (float*)d_ws;
  unsigned short* wsh = (unsigned short*)(wsf + 1191936);
  float* accp = wsf + 393216;
  float* Sp   = wsf + 1179648;

  prep_kernel<<<dim3(864), 256, 0, stream>>>(x, Win, Wout, wsh);
  proj_kernel<<<dim3(12, 80), 256, 0, stream>>>(wsh, bin, wsf, wsh);
  attn_kernel<<<dim3(768), 256, 0, stream>>>(wsf, wsh, accp, Sp);
  norm_kernel<<<dim3(96), 256, 0, stream>>>(accp, Sp, wsh);
  outp_kernel<<<dim3(12, 16), 256, 0, stream>>>(wsh, bout, (float*)d_out);
}

// Round 6
// 174.596 us; speedup vs baseline: 1.2839x; 1.2839x over previous
//
#include <hip/hip_runtime.h>
#include <hip/hip_bf16.h>

// ---------------------------------------------------------------------------
// TwoSimplicialAttention  (B=2, T=192, C=512, H=8, D=64)
// R6: R5's in-lane-P attn (no P LDS round-trip) with register pressure halved:
//     single-kstep processing (no A/B pairing), launch_bounds(256,2) so the
//     allocator never spills (R5's (256,3) cap forced 84 VGPR + 370MB scratch
//     traffic). K1/V1 in LDS (51.2KB -> 3 blocks/CU), k2/v2 global+prefetch.
// ---------------------------------------------------------------------------

typedef float  v4f __attribute__((ext_vector_type(4)));
typedef short  v8s __attribute__((ext_vector_type(8)));

__device__ __forceinline__ unsigned short f2bf(float f) {
  unsigned u = __float_as_uint(f);
  u += 0x7fffu + ((u >> 16) & 1u);       // RNE
  return (unsigned short)(u >> 16);
}
__device__ __forceinline__ float bf2f(unsigned short b) {
  return __uint_as_float(((unsigned)b) << 16);
}
__device__ __forceinline__ unsigned pack_bf16(float lo, float hi) {
  __hip_bfloat162 t = __float22bfloat162_rn(float2{lo, hi});
  union { __hip_bfloat162 b; unsigned u; } cv;
  cv.b = t;
  return cv.u;
}

#if __has_builtin(__builtin_amdgcn_exp2f)
#define EXP2F(x) __builtin_amdgcn_exp2f(x)
#else
#define EXP2F(x) exp2f(x)
#endif

#define MFMA32(a, b, c) __builtin_amdgcn_mfma_f32_16x16x32_bf16((a), (b), (c), 0, 0, 0)

// q scale = D^-0.5 * log2(e)
#define QSCALE 0.18033688011112042f

// ws layout, floats (wsf):
//   qs   [16][192][64]        @ 0        (q * 0.125*log2e, fp32)
//   v2p  [16][192][16][4]     @ 196608   ([.][k][c][r] = v2[d=c+16r], fp32)
//   accp [16][12][4][16][64]  @ 393216
//   Sp   [16][12][4][16]      @ 1179648  (total fp32: 1191936)
// ws layout, ushort (wsh = wsf + 1191936):
//   k1b  [16][192][64]  @ 0
//   k2b  [16][192][64]  @ 196608
//   v1t  [16][64][192]  @ 393216   (columns in sigma-order, see v1perm)
//   xh   [384][512]     @ 589824      xl @ 786432
//   Wth  [2560][512]    @ 983040      Wtl @ 2293760   (W_in^T, k-major)
//   Woth [512][512]     @ 3604480     Wotl @ 3866624  (W_out^T, k-major)
//   oh   [384][512]     @ 4128768     ol  @ 4325376   (normalized out)

#define XH_OFF   589824
#define XL_OFF   786432
#define WTH_OFF  983040
#define WTL_OFF  2293760
#define WOTH_OFF 3604480
#define WOTL_OFF 3866624
#define OH_OFF   4128768
#define OL_OFF   4325376

// sigma: V1 column position p for actual j index t (0..191).
// PV A-frag dword w of m-group m = pack(C[2m+(w>>1)][(w&1)*2 +{0,1}]) in-lane.
__device__ __forceinline__ int v1perm(int t) {
  const int h = (t >= 96) ? 1 : 0;
  const int jh = t - 96 * h;
  const int jtl = jh >> 4, rem = jh & 15;
  const int m = jtl >> 1;
  const int w = ((jtl & 1) << 1) | ((rem >> 1) & 1);
  const int k = ((rem >> 2) << 3) | (w << 1) | (rem & 1);
  return h * 96 + m * 32 + k;
}

// ------------------------------ Phase 0: prep ------------------------------
__global__ __launch_bounds__(256) void prep_kernel(
    const float* __restrict__ x, const float* __restrict__ Win,
    const float* __restrict__ Wout, unsigned short* __restrict__ wsh) {
  __shared__ float tile[32 * 65];
  const int bi = blockIdx.x, t = threadIdx.x;
  if (bi < 768) {
    const float* W; unsigned short *Th, *Tl; int R, n0, k0;
    if (bi < 640) {
      W = Win; Th = wsh + WTH_OFF; Tl = wsh + WTL_OFF; R = 2560;
      n0 = (bi % 40) << 6; k0 = (bi / 40) << 5;
    } else {
      const int idx = bi - 640;
      W = Wout; Th = wsh + WOTH_OFF; Tl = wsh + WOTL_OFF; R = 512;
      n0 = (idx & 7) << 6; k0 = (idx >> 3) << 5;
    }
    const int n = t & 63, kq = (t >> 6) * 8;
#pragma unroll
    for (int j = 0; j < 8; ++j)
      tile[(kq + j) * 65 + n] = W[(k0 + kq + j) * R + n0 + n];
    __syncthreads();
    const int n2 = t >> 2, ks = (t & 3) * 8;
    union { uint4 u; unsigned short us[8]; } ph, pl;
#pragma unroll
    for (int j = 0; j < 8; ++j) {
      const float v = tile[(ks + j) * 65 + n2];
      const unsigned short h = f2bf(v);
      ph.us[j] = h;
      pl.us[j] = f2bf(v - bf2f(h));
    }
    *(uint4*)(Th + (n0 + n2) * 512 + k0 + ks) = ph.u;
    *(uint4*)(Tl + (n0 + n2) * 512 + k0 + ks) = pl.u;
  } else {
    const int flat = ((bi - 768) * 256 + t) * 8;
    const v4f v0 = *(const v4f*)(x + flat);
    const v4f v1 = *(const v4f*)(x + flat + 4);
    union { uint4 u; unsigned short us[8]; } ph, pl;
#pragma unroll
    for (int j = 0; j < 4; ++j) {
      unsigned short h = f2bf(v0[j]);
      ph.us[j] = h; pl.us[j] = f2bf(v0[j] - bf2f(h));
      h = f2bf(v1[j]);
      ph.us[4 + j] = h; pl.us[4 + j] = f2bf(v1[j] - bf2f(h));
    }
    *(uint4*)(wsh + XH_OFF + flat) = ph.u;
    *(uint4*)(wsh + XL_OFF + flat) = pl.u;
  }
}

// ------------------------------ Phase 1: proj (bf16x3 MFMA) ----------------
// grid (12, 80) x 256 thr: 4 waves split K=512 (128 each), 32x32 C-tile.
__global__ __launch_bounds__(256) void proj_kernel(
    const unsigned short* __restrict__ wsh, const float* __restrict__ bin,
    float* __restrict__ wsf, unsigned short* __restrict__ wshd) {
  __shared__ float red[4][32][33];
  const int tid = threadIdx.x;
  const int wv = tid >> 6, lane = tid & 63;
  const int c = lane & 15, q = lane >> 4;
  const int bm = blockIdx.x, bn = blockIdx.y;
  const int k0 = wv * 128;

  const unsigned short* base[8];
  base[0] = wsh + XH_OFF + (bm * 32 + c) * 512 + (q << 3) + k0;
  base[1] = base[0] + 16 * 512;
  base[2] = wsh + XL_OFF + (bm * 32 + c) * 512 + (q << 3) + k0;
  base[3] = base[2] + 16 * 512;
  base[4] = wsh + WTH_OFF + (bn * 32 + c) * 512 + (q << 3) + k0;
  base[5] = base[4] + 16 * 512;
  base[6] = wsh + WTL_OFF + (bn * 32 + c) * 512 + (q << 3) + k0;
  base[7] = base[6] + 16 * 512;

  const v4f z = {0.f, 0.f, 0.f, 0.f};
  v4f a00 = z, a01 = z, a10 = z, a11 = z;

  v8s cur[8], nxt[8];
#pragma unroll
  for (int i = 0; i < 8; ++i) cur[i] = *(const v8s*)(base[i]);
#pragma unroll 1
  for (int ks = 0; ks < 4; ++ks) {
    if (ks < 3) {
      const int o = (ks + 1) * 32;
#pragma unroll
      for (int i = 0; i < 8; ++i) nxt[i] = *(const v8s*)(base[i] + o);
    }
    a00 = MFMA32(cur[2], cur[4], a00); a00 = MFMA32(cur[0], cur[6], a00); a00 = MFMA32(cur[0], cur[4], a00);
    a01 = MFMA32(cur[2], cur[5], a01); a01 = MFMA32(cur[0], cur[7], a01); a01 = MFMA32(cur[0], cur[5], a01);
    a10 = MFMA32(cur[3], cur[4], a10); a10 = MFMA32(cur[1], cur[6], a10); a10 = MFMA32(cur[1], cur[4], a10);
    a11 = MFMA32(cur[3], cur[5], a11); a11 = MFMA32(cur[1], cur[7], a11); a11 = MFMA32(cur[1], cur[5], a11);
#pragma unroll
    for (int i = 0; i < 8; ++i) cur[i] = nxt[i];
  }

  v4f accs[2][2] = {{a00, a01}, {a10, a11}};
#pragma unroll
  for (int mt = 0; mt < 2; ++mt)
#pragma unroll
    for (int nt = 0; nt < 2; ++nt)
#pragma unroll
      for (int r = 0; r < 4; ++r)
        red[wv][mt * 16 + (q << 2) + r][nt * 16 + c] = accs[mt][nt][r];
  __syncthreads();

#pragma unroll
  for (int j = 0; j < 4; ++j) {
    const int o = tid + (j << 8);
    const int row = o >> 5, col = o & 31;
    const int n = bn * 32 + col;
    const float val = red[0][row][col] + red[1][row][col] +
                      red[2][row][col] + red[3][row][col] + bin[n];
    const int m = bm * 32 + row;
    const int which = n >> 9, cc = n & 511, hh = cc >> 6, d = cc & 63;
    const int b = (m >= 192) ? 1 : 0;
    const int tt = m - (b ? 192 : 0);
    const int bh = b * 8 + hh;
    const int rm = ((bh * 192 + tt) << 6) + d;
    if (which == 0)      wsf[rm] = val * QSCALE;
    else if (which == 1) wshd[rm] = f2bf(val);
    else if (which == 2) wshd[393216 + ((bh << 6) + d) * 192 + v1perm(tt)] = f2bf(val);
    else if (which == 3) wshd[196608 + rm] = f2bf(val);
    else wsf[196608 + ((bh * 192 + tt) * 16 + (d & 15)) * 4 + (d >> 4)] = val;
  }
}

// ------------------------------ Phase 2: attention -------------------------
// grid = 16(bh)*12(i)*4(ksplit) = 768 blocks, 256 thr (4 waves), 3 blocks/CU
// (LDS-capped). Single-kstep inner loop; P never touches LDS (in-lane pack).
__global__ __launch_bounds__(256, 2) void attn_kernel(
    const float* __restrict__ wsf, const unsigned short* __restrict__ wsh,
    float* __restrict__ accp, float* __restrict__ Sp) {
  __shared__ unsigned short smem[25600];   // V1s [64][196] + K1s [192][68] = 51200 B
  unsigned short* V1s = smem;
  unsigned short* K1s = smem + 12544;

  const int tid  = threadIdx.x;
  const int wv   = tid >> 6;
  const int lane = tid & 63;
  const int c    = lane & 15;
  const int quad = lane >> 4;

  const int bb = blockIdx.x;
  const int kb = bb & 3;
  const int it = (bb >> 2) % 12;
  const int bh = bb / 48;

  const unsigned short* k1g = wsh + bh * 192 * 64;
  const unsigned short* v1g = wsh + 393216 + bh * 64 * 192;
  const unsigned short* k2g = wsh + 196608 + bh * 192 * 64;
  const float*          v2g = wsf + 196608 + bh * 12288;   // [192][16][4]

  for (int idx = tid; idx < 3072; idx += 256) {
    if (idx < 1536) {
      const int r = idx / 24, c8 = (idx % 24) * 8;
      *(uint4*)(V1s + r * 196 + c8) = *(const uint4*)(v1g + r * 192 + c8);
    } else {
      const int j = idx - 1536;
      const int r = j >> 3, c8 = (j & 7) << 3;
      *(uint4*)(K1s + r * 68 + c8) = *(const uint4*)(k1g + (r << 6) + c8);
    }
  }

  // q rows (fp32, pre-scaled): i = it*16+c, d = quad*8+e (+32)
  const float* qg = wsf + ((bh * 192 + it * 16 + c) << 6) + (quad << 3);
  float q0[8], q1[8];
  {
    v4f qa = *(const v4f*)(qg), qb = *(const v4f*)(qg + 4);
    v4f qc = *(const v4f*)(qg + 32), qd = *(const v4f*)(qg + 36);
#pragma unroll
    for (int e = 0; e < 4; ++e) {
      q0[e] = qa[e]; q0[4 + e] = qb[e];
      q1[e] = qc[e]; q1[4 + e] = qd[e];
    }
  }
  __syncthreads();   // staging done; no barriers until epilogue

  const v4f z = {0.f, 0.f, 0.f, 0.f};
  v4f acc[4] = {z, z, z, z};
  v4f oS = z;
  const short one = (short)0x3F80;
  const v8s ones = {one, one, one, one, one, one, one, one};

  const int kstart = kb * 48 + wv * 12;
  union U4 { uint4 u4; unsigned short us[8]; };
  union AF { v8s v; unsigned u[4]; };

  U4 kl, kh, nkl, nkh;
  kl.u4 = *(const uint4*)(k2g + (kstart << 6) + (quad << 3));
  kh.u4 = *(const uint4*)(k2g + (kstart << 6) + (quad << 3) + 32);
  v4f v2 = *(const v4f*)(v2g + (kstart << 6) + (c << 2));

#pragma unroll 1
  for (int s = 0; s < 12; ++s) {
    v4f nv2;
    if (s < 11) {   // prefetch next kstep's k2 / v2
      const int o = ((kstart + s + 1) << 6);
      nkl.u4 = *(const uint4*)(k2g + o + (quad << 3));
      nkh.u4 = *(const uint4*)(k2g + o + (quad << 3) + 32);
      nv2 = *(const v4f*)(v2g + o + (c << 2));
    }

    AF af0, af1;
#pragma unroll
    for (int e = 0; e < 4; ++e) {
      af0.u[e] = pack_bf16(q0[2*e] * bf2f(kl.us[2*e]), q0[2*e+1] * bf2f(kl.us[2*e+1]));
      af1.u[e] = pack_bf16(q1[2*e] * bf2f(kh.us[2*e]), q1[2*e+1] * bf2f(kh.us[2*e+1]));
    }

    v4f o[4] = {z, z, z, z};
#pragma unroll
    for (int h = 0; h < 2; ++h) {
      // logits: A = K1 (m=j), B = Q*k2 (n=i) -> lane holds P[i=c][j=jt*16+q*4+r]
      v4f C[6];
#pragma unroll
      for (int j6 = 0; j6 < 6; ++j6) {
        const unsigned short* kp = K1s + ((h * 6 + j6) * 16 + c) * 68 + (quad << 3);
        v4f t0 = MFMA32(*(const v8s*)kp, af0.v, z);
        C[j6] = MFMA32(*(const v8s*)(kp + 32), af1.v, t0);
      }
#pragma unroll
      for (int j6 = 0; j6 < 6; ++j6)
#pragma unroll
        for (int r = 0; r < 4; ++r) C[j6][r] = EXP2F(C[j6][r]);
      // in-lane A-frag construction (sigma-matched to V1 column order)
      AF p[3];
#pragma unroll
      for (int m = 0; m < 3; ++m)
#pragma unroll
        for (int w = 0; w < 4; ++w) {
          const int jt = 2 * m + (w >> 1), r0 = (w & 1) * 2;
          p[m].u[w] = pack_bf16(C[jt][r0], C[jt][r0 + 1]);
        }
      // PV + S
#pragma unroll
      for (int m = 0; m < 3; ++m) {
        oS = MFMA32(p[m].v, ones, oS);
        const int vcol = (h * 3 + m) * 32 + (quad << 3);
#pragma unroll
        for (int t = 0; t < 4; ++t) {
          const v8s vf = *(const v8s*)(V1s + (c + 16 * t) * 196 + vcol);
          o[t] = MFMA32(p[m].v, vf, o[t]);
        }
      }
    }
#pragma unroll
    for (int t = 0; t < 4; ++t) acc[t] += o[t] * v2[t];
    kl = nkl; kh = nkh; v2 = nv2;
  }

  __syncthreads();  // reuse smem for cross-wave reduction
  float* redA = (float*)smem;              // [4][16][64]
  float* redS = (float*)smem + 4096;       // [4][16]

  if (c == 0) {
    float* rs = redS + wv * 16 + (quad << 2);
#pragma unroll
    for (int r = 0; r < 4; ++r) rs[r] = oS[r];
  }
#pragma unroll
  for (int r = 0; r < 4; ++r) {
    float* rr = redA + wv * 1024 + (((quad << 2) + r) << 6) + c;
    rr[0] = acc[0][r]; rr[16] = acc[1][r]; rr[32] = acc[2][r]; rr[48] = acc[3][r];
  }
  __syncthreads();

  const int pbase = (bh * 12 + it) * 4 + kb;
  float* ap_out = accp + pbase * 1024;
  for (int idx = tid; idx < 1024; idx += 256)
    ap_out[idx] = redA[idx] + redA[1024 + idx] + redA[2048 + idx] + redA[3072 + idx];
  if (tid < 16)
    Sp[pbase * 16 + tid] = redS[tid] + redS[16 + tid] + redS[32 + tid] + redS[48 + tid];
}

// ------------------------------ Phase 2.5: normalize -----------------------
__global__ __launch_bounds__(256) void norm_kernel(
    const float* __restrict__ accp, const float* __restrict__ Sp,
    unsigned short* __restrict__ wsh) {
  const int flat = blockIdx.x * 2048 + threadIdx.x * 8;
  const int m = flat >> 9, cc = flat & 511;
  const int b = (m >= 192) ? 1 : 0;
  const int tt = m - (b ? 192 : 0);
  const int h = cc >> 6, d0 = cc & 63;
  const int bh = b * 8 + h, it = tt >> 4, i = tt & 15;
  const int pb = (bh * 12 + it) * 4;
  const float* ap = accp + pb * 1024 + (i << 6) + d0;
  v4f a0 = *(const v4f*)(ap), a1 = *(const v4f*)(ap + 4);
  float Sv = Sp[pb * 16 + i];
#pragma unroll
  for (int kb = 1; kb < 4; ++kb) {
    a0 += *(const v4f*)(ap + kb * 1024);
    a1 += *(const v4f*)(ap + kb * 1024 + 4);
    Sv += Sp[(pb + kb) * 16 + i];
  }
  const float inv = 1.0f / Sv;
  union { uint4 u; unsigned short us[8]; } ph, pl;
#pragma unroll
  for (int j = 0; j < 4; ++j) {
    float v = a0[j] * inv;
    unsigned short hh = f2bf(v);
    ph.us[j] = hh; pl.us[j] = f2bf(v - bf2f(hh));
    v = a1[j] * inv;
    hh = f2bf(v);
    ph.us[4 + j] = hh; pl.us[4 + j] = f2bf(v - bf2f(hh));
  }
  *(uint4*)(wsh + OH_OFF + flat) = ph.u;
  *(uint4*)(wsh + OL_OFF + flat) = pl.u;
}

// ------------------------------ Phase 3: out GEMM (bf16x3 MFMA) ------------
// grid (12, 16) x 256 thr: 4 waves split K=512, 32x32 tile, LDS combine.
__global__ __launch_bounds__(256) void outp_kernel(
    const unsigned short* __restrict__ wsh, const float* __restrict__ bout,
    float* __restrict__ y) {
  __shared__ float red[4][32][33];
  const int tid = threadIdx.x;
  const int wv = tid >> 6, lane = tid & 63;
  const int c = lane & 15, q = lane >> 4;
  const int bm = blockIdx.x, bn = blockIdx.y;
  const int k0 = wv * 128;

  const unsigned short* base[8];
  base[0] = wsh + OH_OFF + (bm * 32 + c) * 512 + (q << 3) + k0;
  base[1] = base[0] + 16 * 512;
  base[2] = wsh + OL_OFF + (bm * 32 + c) * 512 + (q << 3) + k0;
  base[3] = base[2] + 16 * 512;
  base[4] = wsh + WOTH_OFF + (bn * 32 + c) * 512 + (q << 3) + k0;
  base[5] = base[4] + 16 * 512;
  base[6] = wsh + WOTL_OFF + (bn * 32 + c) * 512 + (q << 3) + k0;
  base[7] = base[6] + 16 * 512;

  const v4f z = {0.f, 0.f, 0.f, 0.f};
  v4f a00 = z, a01 = z, a10 = z, a11 = z;

  v8s cur[8], nxt[8];
#pragma unroll
  for (int i = 0; i < 8; ++i) cur[i] = *(const v8s*)(base[i]);
#pragma unroll 1
  for (int ks = 0; ks < 4; ++ks) {
    if (ks < 3) {
      const int o = (ks + 1) * 32;
#pragma unroll
      for (int i = 0; i < 8; ++i) nxt[i] = *(const v8s*)(base[i] + o);
    }
    a00 = MFMA32(cur[2], cur[4], a00); a00 = MFMA32(cur[0], cur[6], a00); a00 = MFMA32(cur[0], cur[4], a00);
    a01 = MFMA32(cur[2], cur[5], a01); a01 = MFMA32(cur[0], cur[7], a01); a01 = MFMA32(cur[0], cur[5], a01);
    a10 = MFMA32(cur[3], cur[4], a10); a10 = MFMA32(cur[1], cur[6], a10); a10 = MFMA32(cur[1], cur[4], a10);
    a11 = MFMA32(cur[3], cur[5], a11); a11 = MFMA32(cur[1], cur[7], a11); a11 = MFMA32(cur[1], cur[5], a11);
#pragma unroll
    for (int i = 0; i < 8; ++i) cur[i] = nxt[i];
  }

  v4f accs[2][2] = {{a00, a01}, {a10, a11}};
#pragma unroll
  for (int mt = 0; mt < 2; ++mt)
#pragma unroll
    for (int nt = 0; nt < 2; ++nt)
#pragma unroll
      for (int r = 0; r < 4; ++r)
        red[wv][mt * 16 + (q << 2) + r][nt * 16 + c] = accs[mt][nt][r];
  __syncthreads();

#pragma unroll
  for (int j = 0; j < 4; ++j) {
    const int o = tid + (j << 8);
    const int row = o >> 5, col = o & 31;
    const int n = bn * 32 + col;
    const float val = red[0][row][col] + red[1][row][col] +
                      red[2][row][col] + red[3][row][col] + bout[n];
    y[(bm * 32 + row) * 512 + n] = val;
  }
}

// ------------------------------ launcher -----------------------------------
extern "C" void kernel_launch(void* const* d_in, const int* in_sizes, int n_in,
                              void* d_out, int out_size, void* d_ws, size_t ws_size,
                              hipStream_t stream) {
  const float* x    = (const float*)d_in[0];
  const float* Win  = (const float*)d_in[1];
  const float* bin  = (const float*)d_in[2];
  const float* Wout = (const float*)d_in[3];
  const float* bout = (const float*)d_in[4];

  float* wsf = (float*)d_ws;
  unsigned short* wsh = (unsigned short*)(wsf + 1191936);
  float* accp = wsf + 393216;
  float* Sp   = wsf + 1179648;

  prep_kernel<<<dim3(864), 256, 0, stream>>>(x, Win, Wout, wsh);
  proj_kernel<<<dim3(12, 80), 256, 0, stream>>>(wsh, bin, wsf, wsh);
  attn_kernel<<<dim3(768), 256, 0, stream>>>(wsf, wsh, accp, Sp);
  norm_kernel<<<dim3(96), 256, 0, stream>>>(accp, Sp, wsh);
  outp_kernel<<<dim3(12, 16), 256, 0, stream>>>(wsh, bout, (float*)d_out);
}

// Round 7
// 174.435 us; speedup vs baseline: 1.2851x; 1.0009x over previous
//
#include <hip/hip_runtime.h>
#include <hip/hip_bf16.h>

// ---------------------------------------------------------------------------
// TwoSimplicialAttention  (B=2, T=192, C=512, H=8, D=64)
// R7: attn: launch_bounds(256,1) — the (256,n) min-waves arg was capping VGPR
//     at 512/(2n) (R5: n=3 -> 84, R6: n=2 -> 128) and forcing scratch spill
//     (47MB extra HBM traffic in R6). Softmax-sum moved off the MFMA pipe
//     (lane-local VALU adds + epilogue shfl_xor) — MFMA/kstep 54 -> 48.
//     norm fused into outp (A-frags normalized+split in-register from accp).
// ---------------------------------------------------------------------------

typedef float  v4f __attribute__((ext_vector_type(4)));
typedef short  v8s __attribute__((ext_vector_type(8)));

__device__ __forceinline__ unsigned short f2bf(float f) {
  unsigned u = __float_as_uint(f);
  u += 0x7fffu + ((u >> 16) & 1u);       // RNE
  return (unsigned short)(u >> 16);
}
__device__ __forceinline__ float bf2f(unsigned short b) {
  return __uint_as_float(((unsigned)b) << 16);
}
__device__ __forceinline__ unsigned pack_bf16(float lo, float hi) {
  __hip_bfloat162 t = __float22bfloat162_rn(float2{lo, hi});
  union { __hip_bfloat162 b; unsigned u; } cv;
  cv.b = t;
  return cv.u;
}

#if __has_builtin(__builtin_amdgcn_exp2f)
#define EXP2F(x) __builtin_amdgcn_exp2f(x)
#else
#define EXP2F(x) exp2f(x)
#endif

#define MFMA32(a, b, c) __builtin_amdgcn_mfma_f32_16x16x32_bf16((a), (b), (c), 0, 0, 0)

// q scale = D^-0.5 * log2(e)
#define QSCALE 0.18033688011112042f

// ws layout, floats (wsf):
//   qs   [16][192][64]        @ 0        (q * 0.125*log2e, fp32)
//   v2p  [16][192][16][4]     @ 196608   ([.][k][c][r] = v2[d=c+16r], fp32)
//   accp [16][12][4][16][64]  @ 393216
//   Sp   [16][12][4][16]      @ 1179648  (total fp32: 1191936)
// ws layout, ushort (wsh = wsf + 1191936):
//   k1b  [16][192][64]  @ 0
//   k2b  [16][192][64]  @ 196608
//   v1t  [16][64][192]  @ 393216   (columns in sigma-order, see v1perm)
//   xh   [384][512]     @ 589824      xl @ 786432
//   Wth  [2560][512]    @ 983040      Wtl @ 2293760   (W_in^T, k-major)
//   Woth [512][512]     @ 3604480     Wotl @ 3866624  (W_out^T, k-major)

#define XH_OFF   589824
#define XL_OFF   786432
#define WTH_OFF  983040
#define WTL_OFF  2293760
#define WOTH_OFF 3604480
#define WOTL_OFF 3866624

// sigma: V1 column position p for actual j index t (0..191).
// PV A-frag dword w of m-group m = pack(C[2m+(w>>1)][(w&1)*2 +{0,1}]) in-lane.
__device__ __forceinline__ int v1perm(int t) {
  const int h = (t >= 96) ? 1 : 0;
  const int jh = t - 96 * h;
  const int jtl = jh >> 4, rem = jh & 15;
  const int m = jtl >> 1;
  const int w = ((jtl & 1) << 1) | ((rem >> 1) & 1);
  const int k = ((rem >> 2) << 3) | (w << 1) | (rem & 1);
  return h * 96 + m * 32 + k;
}

// ------------------------------ Phase 0: prep ------------------------------
__global__ __launch_bounds__(256) void prep_kernel(
    const float* __restrict__ x, const float* __restrict__ Win,
    const float* __restrict__ Wout, unsigned short* __restrict__ wsh) {
  __shared__ float tile[32 * 65];
  const int bi = blockIdx.x, t = threadIdx.x;
  if (bi < 768) {
    const float* W; unsigned short *Th, *Tl; int R, n0, k0;
    if (bi < 640) {
      W = Win; Th = wsh + WTH_OFF; Tl = wsh + WTL_OFF; R = 2560;
      n0 = (bi % 40) << 6; k0 = (bi / 40) << 5;
    } else {
      const int idx = bi - 640;
      W = Wout; Th = wsh + WOTH_OFF; Tl = wsh + WOTL_OFF; R = 512;
      n0 = (idx & 7) << 6; k0 = (idx >> 3) << 5;
    }
    const int n = t & 63, kq = (t >> 6) * 8;
#pragma unroll
    for (int j = 0; j < 8; ++j)
      tile[(kq + j) * 65 + n] = W[(k0 + kq + j) * R + n0 + n];
    __syncthreads();
    const int n2 = t >> 2, ks = (t & 3) * 8;
    union { uint4 u; unsigned short us[8]; } ph, pl;
#pragma unroll
    for (int j = 0; j < 8; ++j) {
      const float v = tile[(ks + j) * 65 + n2];
      const unsigned short h = f2bf(v);
      ph.us[j] = h;
      pl.us[j] = f2bf(v - bf2f(h));
    }
    *(uint4*)(Th + (n0 + n2) * 512 + k0 + ks) = ph.u;
    *(uint4*)(Tl + (n0 + n2) * 512 + k0 + ks) = pl.u;
  } else {
    const int flat = ((bi - 768) * 256 + t) * 8;
    const v4f v0 = *(const v4f*)(x + flat);
    const v4f v1 = *(const v4f*)(x + flat + 4);
    union { uint4 u; unsigned short us[8]; } ph, pl;
#pragma unroll
    for (int j = 0; j < 4; ++j) {
      unsigned short h = f2bf(v0[j]);
      ph.us[j] = h; pl.us[j] = f2bf(v0[j] - bf2f(h));
      h = f2bf(v1[j]);
      ph.us[4 + j] = h; pl.us[4 + j] = f2bf(v1[j] - bf2f(h));
    }
    *(uint4*)(wsh + XH_OFF + flat) = ph.u;
    *(uint4*)(wsh + XL_OFF + flat) = pl.u;
  }
}

// ------------------------------ Phase 1: proj (bf16x3 MFMA) ----------------
// grid (12, 80) x 256 thr: 4 waves split K=512 (128 each), 32x32 C-tile.
__global__ __launch_bounds__(256) void proj_kernel(
    const unsigned short* __restrict__ wsh, const float* __restrict__ bin,
    float* __restrict__ wsf, unsigned short* __restrict__ wshd) {
  __shared__ float red[4][32][33];
  const int tid = threadIdx.x;
  const int wv = tid >> 6, lane = tid & 63;
  const int c = lane & 15, q = lane >> 4;
  const int bm = blockIdx.x, bn = blockIdx.y;
  const int k0 = wv * 128;

  const unsigned short* base[8];
  base[0] = wsh + XH_OFF + (bm * 32 + c) * 512 + (q << 3) + k0;
  base[1] = base[0] + 16 * 512;
  base[2] = wsh + XL_OFF + (bm * 32 + c) * 512 + (q << 3) + k0;
  base[3] = base[2] + 16 * 512;
  base[4] = wsh + WTH_OFF + (bn * 32 + c) * 512 + (q << 3) + k0;
  base[5] = base[4] + 16 * 512;
  base[6] = wsh + WTL_OFF + (bn * 32 + c) * 512 + (q << 3) + k0;
  base[7] = base[6] + 16 * 512;

  const v4f z = {0.f, 0.f, 0.f, 0.f};
  v4f a00 = z, a01 = z, a10 = z, a11 = z;

  v8s cur[8], nxt[8];
#pragma unroll
  for (int i = 0; i < 8; ++i) cur[i] = *(const v8s*)(base[i]);
#pragma unroll 1
  for (int ks = 0; ks < 4; ++ks) {
    if (ks < 3) {
      const int o = (ks + 1) * 32;
#pragma unroll
      for (int i = 0; i < 8; ++i) nxt[i] = *(const v8s*)(base[i] + o);
    }
    a00 = MFMA32(cur[2], cur[4], a00); a00 = MFMA32(cur[0], cur[6], a00); a00 = MFMA32(cur[0], cur[4], a00);
    a01 = MFMA32(cur[2], cur[5], a01); a01 = MFMA32(cur[0], cur[7], a01); a01 = MFMA32(cur[0], cur[5], a01);
    a10 = MFMA32(cur[3], cur[4], a10); a10 = MFMA32(cur[1], cur[6], a10); a10 = MFMA32(cur[1], cur[4], a10);
    a11 = MFMA32(cur[3], cur[5], a11); a11 = MFMA32(cur[1], cur[7], a11); a11 = MFMA32(cur[1], cur[5], a11);
#pragma unroll
    for (int i = 0; i < 8; ++i) cur[i] = nxt[i];
  }

  v4f accs[2][2] = {{a00, a01}, {a10, a11}};
#pragma unroll
  for (int mt = 0; mt < 2; ++mt)
#pragma unroll
    for (int nt = 0; nt < 2; ++nt)
#pragma unroll
      for (int r = 0; r < 4; ++r)
        red[wv][mt * 16 + (q << 2) + r][nt * 16 + c] = accs[mt][nt][r];
  __syncthreads();

#pragma unroll
  for (int j = 0; j < 4; ++j) {
    const int o = tid + (j << 8);
    const int row = o >> 5, col = o & 31;
    const int n = bn * 32 + col;
    const float val = red[0][row][col] + red[1][row][col] +
                      red[2][row][col] + red[3][row][col] + bin[n];
    const int m = bm * 32 + row;
    const int which = n >> 9, cc = n & 511, hh = cc >> 6, d = cc & 63;
    const int b = (m >= 192) ? 1 : 0;
    const int tt = m - (b ? 192 : 0);
    const int bh = b * 8 + hh;
    const int rm = ((bh * 192 + tt) << 6) + d;
    if (which == 0)      wsf[rm] = val * QSCALE;
    else if (which == 1) wshd[rm] = f2bf(val);
    else if (which == 2) wshd[393216 + ((bh << 6) + d) * 192 + v1perm(tt)] = f2bf(val);
    else if (which == 3) wshd[196608 + rm] = f2bf(val);
    else wsf[196608 + ((bh * 192 + tt) * 16 + (d & 15)) * 4 + (d >> 4)] = val;
  }
}

// ------------------------------ Phase 2: attention -------------------------
// grid = 16(bh)*12(i)*4(ksplit) = 768 blocks, 256 thr (4 waves).
// launch_bounds(256,1): no artificial VGPR cap (demand ~160 -> 3 waves/SIMD,
// 3 blocks/CU, exactly one round). In-lane P; S via lane-local VALU adds.
__global__ __launch_bounds__(256, 1) void attn_kernel(
    const float* __restrict__ wsf, const unsigned short* __restrict__ wsh,
    float* __restrict__ accp, float* __restrict__ Sp) {
  __shared__ unsigned short smem[25600];   // V1s [64][196] + K1s [192][68] = 51200 B
  unsigned short* V1s = smem;
  unsigned short* K1s = smem + 12544;

  const int tid  = threadIdx.x;
  const int wv   = tid >> 6;
  const int lane = tid & 63;
  const int c    = lane & 15;
  const int quad = lane >> 4;

  const int bb = blockIdx.x;
  const int kb = bb & 3;
  const int it = (bb >> 2) % 12;
  const int bh = bb / 48;

  const unsigned short* k1g = wsh + bh * 192 * 64;
  const unsigned short* v1g = wsh + 393216 + bh * 64 * 192;
  const unsigned short* k2g = wsh + 196608 + bh * 192 * 64;
  const float*          v2g = wsf + 196608 + bh * 12288;   // [192][16][4]

  for (int idx = tid; idx < 3072; idx += 256) {
    if (idx < 1536) {
      const int r = idx / 24, c8 = (idx % 24) * 8;
      *(uint4*)(V1s + r * 196 + c8) = *(const uint4*)(v1g + r * 192 + c8);
    } else {
      const int j = idx - 1536;
      const int r = j >> 3, c8 = (j & 7) << 3;
      *(uint4*)(K1s + r * 68 + c8) = *(const uint4*)(k1g + (r << 6) + c8);
    }
  }

  // q rows (fp32, pre-scaled): i = it*16+c, d = quad*8+e (+32)
  const float* qg = wsf + ((bh * 192 + it * 16 + c) << 6) + (quad << 3);
  float q0[8], q1[8];
  {
    v4f qa = *(const v4f*)(qg), qb = *(const v4f*)(qg + 4);
    v4f qc = *(const v4f*)(qg + 32), qd = *(const v4f*)(qg + 36);
#pragma unroll
    for (int e = 0; e < 4; ++e) {
      q0[e] = qa[e]; q0[4 + e] = qb[e];
      q1[e] = qc[e]; q1[4 + e] = qd[e];
    }
  }
  __syncthreads();   // staging done; no barriers until epilogue

  const v4f z = {0.f, 0.f, 0.f, 0.f};
  v4f acc[4] = {z, z, z, z};
  float sS = 0.f;

  const int kstart = kb * 48 + wv * 12;
  union U4 { uint4 u4; unsigned short us[8]; };
  union AF { v8s v; unsigned u[4]; };

  U4 kl, kh, nkl, nkh;
  kl.u4 = *(const uint4*)(k2g + (kstart << 6) + (quad << 3));
  kh.u4 = *(const uint4*)(k2g + (kstart << 6) + (quad << 3) + 32);
  v4f v2 = *(const v4f*)(v2g + (kstart << 6) + (c << 2));

#pragma unroll 1
  for (int s = 0; s < 12; ++s) {
    v4f nv2;
    if (s < 11) {   // prefetch next kstep's k2 / v2
      const int o = ((kstart + s + 1) << 6);
      nkl.u4 = *(const uint4*)(k2g + o + (quad << 3));
      nkh.u4 = *(const uint4*)(k2g + o + (quad << 3) + 32);
      nv2 = *(const v4f*)(v2g + o + (c << 2));
    }

    AF af0, af1;
#pragma unroll
    for (int e = 0; e < 4; ++e) {
      af0.u[e] = pack_bf16(q0[2*e] * bf2f(kl.us[2*e]), q0[2*e+1] * bf2f(kl.us[2*e+1]));
      af1.u[e] = pack_bf16(q1[2*e] * bf2f(kh.us[2*e]), q1[2*e+1] * bf2f(kh.us[2*e+1]));
    }

    v4f o[4] = {z, z, z, z};
#pragma unroll
    for (int h = 0; h < 2; ++h) {
      // logits: A = K1 (m=j), B = Q*k2 (n=i) -> lane holds P[j=jt*16+q*4+r][i=c]
      v4f C[6];
#pragma unroll
      for (int j6 = 0; j6 < 6; ++j6) {
        const unsigned short* kp = K1s + ((h * 6 + j6) * 16 + c) * 68 + (quad << 3);
        v4f t0 = MFMA32(*(const v8s*)kp, af0.v, z);
        C[j6] = MFMA32(*(const v8s*)(kp + 32), af1.v, t0);
      }
#pragma unroll
      for (int j6 = 0; j6 < 6; ++j6)
#pragma unroll
        for (int r = 0; r < 4; ++r) {
          C[j6][r] = EXP2F(C[j6][r]);
          sS += C[j6][r];                    // S off the MFMA pipe
        }
      // in-lane A-frag construction (sigma-matched to V1 column order)
      AF p[3];
#pragma unroll
      for (int m = 0; m < 3; ++m)
#pragma unroll
        for (int w = 0; w < 4; ++w) {
          const int jt = 2 * m + (w >> 1), r0 = (w & 1) * 2;
          p[m].u[w] = pack_bf16(C[jt][r0], C[jt][r0 + 1]);
        }
      // PV
#pragma unroll
      for (int m = 0; m < 3; ++m) {
        const int vcol = (h * 3 + m) * 32 + (quad << 3);
#pragma unroll
        for (int t = 0; t < 4; ++t) {
          const v8s vf = *(const v8s*)(V1s + (c + 16 * t) * 196 + vcol);
          o[t] = MFMA32(p[m].v, vf, o[t]);
        }
      }
    }
#pragma unroll
    for (int t = 0; t < 4; ++t) acc[t] += o[t] * v2[t];
    kl = nkl; kh = nkh; v2 = nv2;
  }

  __syncthreads();  // reuse smem for cross-wave reduction
  float* redA = (float*)smem;              // [4][16][64]
  float* redS = (float*)smem + 4096;       // [4][16]

  // S: sum the 4 quads' partials (all share i=c)
  sS += __shfl_xor(sS, 16, 64);
  sS += __shfl_xor(sS, 32, 64);
  if (quad == 0) redS[wv * 16 + c] = sS;
#pragma unroll
  for (int r = 0; r < 4; ++r) {
    float* rr = redA + wv * 1024 + (((quad << 2) + r) << 6) + c;
    rr[0] = acc[0][r]; rr[16] = acc[1][r]; rr[32] = acc[2][r]; rr[48] = acc[3][r];
  }
  __syncthreads();

  const int pbase = (bh * 12 + it) * 4 + kb;
  float* ap_out = accp + pbase * 1024;
  for (int idx = tid; idx < 1024; idx += 256)
    ap_out[idx] = redA[idx] + redA[1024 + idx] + redA[2048 + idx] + redA[3072 + idx];
  if (tid < 16)
    Sp[pbase * 16 + tid] = redS[tid] + redS[16 + tid] + redS[32 + tid] + redS[48 + tid];
}

// ------------------------------ Phase 3: norm + out GEMM (bf16x3 MFMA) -----
// grid (12, 16) x 256 thr: 4 waves split K=512; A-frags built in-register
// from accp (sum 4 ksplits, scale by 1/S, hi/lo split). Wave covers 2 heads.
__global__ __launch_bounds__(256) void outp_kernel(
    const float* __restrict__ accp, const float* __restrict__ Sp,
    const unsigned short* __restrict__ wsh, const float* __restrict__ bout,
    float* __restrict__ y) {
  __shared__ float red[4][32][33];
  const int tid = threadIdx.x;
  const int wv = tid >> 6, lane = tid & 63;
  const int c = lane & 15, q = lane >> 4;
  const int bm = blockIdx.x, bn = blockIdx.y;
  const int k0 = wv * 128;

  // per-row (mt) and per-head-within-wave (hh) normalization setup
  int pbase_[2][2];
  float inv_[2][2];
#pragma unroll
  for (int mt = 0; mt < 2; ++mt) {
    const int m = bm * 32 + mt * 16 + c;
    const int b = (m >= 192) ? 1 : 0;
    const int t = m - (b ? 192 : 0);
    const int it = t >> 4, i = t & 15;
#pragma unroll
    for (int hh = 0; hh < 2; ++hh) {
      const int bh = b * 8 + wv * 2 + hh;
      const int pb = (bh * 12 + it) * 4;
      pbase_[mt][hh] = pb * 1024 + (i << 6);
      const float Sv = Sp[pb * 16 + i] + Sp[(pb + 1) * 16 + i] +
                       Sp[(pb + 2) * 16 + i] + Sp[(pb + 3) * 16 + i];
      inv_[mt][hh] = 1.0f / Sv;
    }
  }

  const unsigned short* bh0 = wsh + WOTH_OFF + (bn * 32 + c) * 512 + (q << 3) + k0;
  const unsigned short* bh1 = bh0 + 16 * 512;
  const unsigned short* bl0 = wsh + WOTL_OFF + (bn * 32 + c) * 512 + (q << 3) + k0;
  const unsigned short* bl1 = bl0 + 16 * 512;

  const v4f z = {0.f, 0.f, 0.f, 0.f};
  v4f a00 = z, a01 = z, a10 = z, a11 = z;

#pragma unroll
  for (int ks = 0; ks < 4; ++ks) {
    const int hh = ks >> 1;
    const int d0 = (ks & 1) * 32 + (q << 3);
    v8s Ah[2], Al[2];
#pragma unroll
    for (int mt = 0; mt < 2; ++mt) {
      const float* ap = accp + pbase_[mt][hh] + d0;
      v4f s0 = *(const v4f*)(ap) + *(const v4f*)(ap + 1024) +
               *(const v4f*)(ap + 2048) + *(const v4f*)(ap + 3072);
      v4f s1 = *(const v4f*)(ap + 4) + *(const v4f*)(ap + 1028) +
               *(const v4f*)(ap + 2052) + *(const v4f*)(ap + 3076);
      const float iv = inv_[mt][hh];
      union { v8s v; unsigned short us[8]; } hfr, lfr;
#pragma unroll
      for (int e = 0; e < 4; ++e) {
        float v0 = s0[e] * iv;
        unsigned short hb = f2bf(v0);
        hfr.us[e] = hb; lfr.us[e] = f2bf(v0 - bf2f(hb));
        float v1 = s1[e] * iv;
        hb = f2bf(v1);
        hfr.us[4 + e] = hb; lfr.us[4 + e] = f2bf(v1 - bf2f(hb));
      }
      Ah[mt] = hfr.v; Al[mt] = lfr.v;
    }
    const int o = ks * 32;
    const v8s Bh0 = *(const v8s*)(bh0 + o), Bh1 = *(const v8s*)(bh1 + o);
    const v8s Bl0 = *(const v8s*)(bl0 + o), Bl1 = *(const v8s*)(bl1 + o);
    a00 = MFMA32(Al[0], Bh0, a00); a00 = MFMA32(Ah[0], Bl0, a00); a00 = MFMA32(Ah[0], Bh0, a00);
    a01 = MFMA32(Al[0], Bh1, a01); a01 = MFMA32(Ah[0], Bl1, a01); a01 = MFMA32(Ah[0], Bh1, a01);
    a10 = MFMA32(Al[1], Bh0, a10); a10 = MFMA32(Ah[1], Bl0, a10); a10 = MFMA32(Ah[1], Bh0, a10);
    a11 = MFMA32(Al[1], Bh1, a11); a11 = MFMA32(Ah[1], Bl1, a11); a11 = MFMA32(Ah[1], Bh1, a11);
  }

  v4f accs[2][2] = {{a00, a01}, {a10, a11}};
#pragma unroll
  for (int mt = 0; mt < 2; ++mt)
#pragma unroll
    for (int nt = 0; nt < 2; ++nt)
#pragma unroll
      for (int r = 0; r < 4; ++r)
        red[wv][mt * 16 + (q << 2) + r][nt * 16 + c] = accs[mt][nt][r];
  __syncthreads();

#pragma unroll
  for (int j = 0; j < 4; ++j) {
    const int o = tid + (j << 8);
    const int row = o >> 5, col = o & 31;
    const int n = bn * 32 + col;
    const float val = red[0][row][col] + red[1][row][col] +
                      red[2][row][col] + red[3][row][col] + bout[n];
    y[(bm * 32 + row) * 512 + n] = val;
  }
}

// ------------------------------ launcher -----------------------------------
extern "C" void kernel_launch(void* const* d_in, const int* in_sizes, int n_in,
                              void* d_out, int out_size, void* d_ws, size_t ws_size,
                              hipStream_t stream) {
  const float* x    = (const float*)d_in[0];
  const float* Win  = (const float*)d_in[1];
  const float* bin  = (const float*)d_in[2];
  const float* Wout = (const float*)d_in[3];
  const float* bout = (const float*)d_in[4];

  float* wsf = (float*)d_ws;
  unsigned short* wsh = (unsigned short*)(wsf + 1191936);
  float* accp = wsf + 393216;
  float* Sp   = wsf + 1179648;

  prep_kernel<<<dim3(864), 256, 0, stream>>>(x, Win, Wout, wsh);
  proj_kernel<<<dim3(12, 80), 256, 0, stream>>>(wsh, bin, wsf, wsh);
  attn_kernel<<<dim3(768), 256, 0, stream>>>(wsf, wsh, accp, Sp);
  outp_kernel<<<dim3(12, 16), 256, 0, stream>>>(accp, Sp, wsh, bout, (float*)d_out);
}